// Round 1
// baseline (219.297 us; speedup 1.0000x reference)
//
#include <hip/hip_runtime.h>

// ---------- types ----------
using bf16x8 = __attribute__((ext_vector_type(8))) __bf16;
using f32x4  = __attribute__((ext_vector_type(4))) float;

#define TWO_LOG2E 2.8853900817779268f

__device__ __forceinline__ unsigned short f2bf(float x) {
  unsigned int u = __float_as_uint(x);
  u = (u + 0x7fffu + ((u >> 16) & 1u)) >> 16;   // RNE
  return (unsigned short)u;
}
__device__ __forceinline__ float bf2f(unsigned short h) {
  return __uint_as_float(((unsigned int)h) << 16);
}
// tanh(x) with s = 2*log2(e)*x prescaled: tanh = 1 - 2/(2^s + 1)
__device__ __forceinline__ float tanh_pre(float s) {
  float e = exp2f(s);                          // v_exp_f32
  float r = __builtin_amdgcn_rcpf(e + 1.0f);   // v_rcp_f32
  return __builtin_fmaf(-2.0f, r, 1.0f);
}

// ---------- 1) cast queries+keys (8192x256) to bf16 hi/lo ----------
__global__ __launch_bounds__(256) void cast_qk_kernel(
    const float* __restrict__ q, const float* __restrict__ k,
    unsigned short* __restrict__ hi, unsigned short* __restrict__ lo) {
  int idx = blockIdx.x * 256 + threadIdx.x;      // float4 id, 0..524287
  int e = idx << 2;
  const float* src = (e < (1 << 20)) ? (q + e) : (k + (e - (1 << 20)));
  float4 v = *(const float4*)src;
  unsigned short h0 = f2bf(v.x), h1 = f2bf(v.y), h2 = f2bf(v.z), h3 = f2bf(v.w);
  *(ushort4*)(hi + e) = make_ushort4(h0, h1, h2, h3);
  *(ushort4*)(lo + e) = make_ushort4(f2bf(v.x - bf2f(h0)), f2bf(v.y - bf2f(h1)),
                                     f2bf(v.z - bf2f(h2)), f2bf(v.w - bf2f(h3)));
}

// ---------- 2) transpose+cast W_q,W_k (->[n][k]) and values (->[b][v][k]) ----------
__global__ __launch_bounds__(256) void cast_t_kernel(
    const float* __restrict__ Wq, const float* __restrict__ Wk, const float* __restrict__ vals,
    unsigned short* __restrict__ wt_hi, unsigned short* __restrict__ wt_lo,
    unsigned short* __restrict__ vt_hi, unsigned short* __restrict__ vt_lo) {
  int idx = blockIdx.x * 256 + threadIdx.x;      // 0..1179647 (18 matrices of 256x256)
  int m = idx >> 16;
  int rem = idx & 65535;
  int r = rem >> 8;    // output row (n or v)
  int c = rem & 255;   // output col (k)
  float x;
  unsigned short *dh, *dl;
  if (m < 2) {
    const float* W = m ? Wk : Wq;
    x = W[c * 256 + r];
    dh = wt_hi + (m << 16) + rem; dl = wt_lo + (m << 16) + rem;
  } else {
    int b = m - 2;
    x = vals[(b << 16) + c * 256 + r];
    dh = vt_hi + (b << 16) + rem; dl = vt_lo + (b << 16) + rem;
  }
  unsigned short h = f2bf(x);
  *dh = h;
  *dl = f2bf(x - bf2f(h));
}

// ---------- 3) projection GEMM: [8192x256] x [256x256] via 16x16x32 bf16 MFMA (hi/lo 3-term)
// Output pre-scaled by 2*log2(e) for the tanh kernel.
__global__ __launch_bounds__(256) void proj_kernel(
    const unsigned short* __restrict__ a_hi, const unsigned short* __restrict__ a_lo,
    const unsigned short* __restrict__ w_hi, const unsigned short* __restrict__ w_lo,
    float* __restrict__ out) {
  int wave = threadIdx.x >> 6, lane = threadIdx.x & 63;
  int m0 = (blockIdx.x * 4 + wave) << 4;   // 0..8176
  int n0 = blockIdx.y << 4;
  int g = m0 >> 12;                        // 0: W_q rows, 1: W_k rows
  int r = lane & 15, qd = lane >> 4;
  int aoff = (m0 + r) * 256 + qd * 8;
  int boff = (g << 16) + (n0 + r) * 256 + qd * 8;
  f32x4 acc = {0.f, 0.f, 0.f, 0.f};
#pragma unroll
  for (int k0 = 0; k0 < 256; k0 += 32) {
    bf16x8 ah = *(const bf16x8*)(a_hi + aoff + k0);
    bf16x8 al = *(const bf16x8*)(a_lo + aoff + k0);
    bf16x8 bh = *(const bf16x8*)(w_hi + boff + k0);
    bf16x8 bl = *(const bf16x8*)(w_lo + boff + k0);
    acc = __builtin_amdgcn_mfma_f32_16x16x32_bf16(ah, bh, acc, 0, 0, 0);
    acc = __builtin_amdgcn_mfma_f32_16x16x32_bf16(ah, bl, acc, 0, 0, 0);
    acc = __builtin_amdgcn_mfma_f32_16x16x32_bf16(al, bh, acc, 0, 0, 0);
  }
#pragma unroll
  for (int i = 0; i < 4; ++i)
    out[(m0 + qd * 4 + i) * 256 + n0 + r] = acc[i] * TWO_LOG2E;
}

// ---------- 4) scores[b][q][k] = sum_h tanh(q'+k') * wv[h]  (q',k' prescaled) ----------
__global__ __launch_bounds__(256) void scores_kernel(
    const float* __restrict__ qp, const float* __restrict__ kp,
    const float* __restrict__ wv, float* __restrict__ scores) {
  __shared__ __align__(16) float qs[32 * 256];
  __shared__ __align__(16) float ks[32 * 256];
  const int t = threadIdx.x;
  const int b = blockIdx.z;
  const int q0 = blockIdx.x << 5;
  const int k0 = blockIdx.y << 5;
  const float* qbase = qp + ((b << 8) + q0) * 256;
  const float* kbase = kp + ((b << 8) + k0) * 256;
  // stage 32x256 q-tile and k-tile, XOR-swizzled to break bank aliasing
#pragma unroll
  for (int i = 0; i < 8; ++i) {
    int cid = t + (i << 8);
    int r = cid >> 6;
    int h = (cid & 63) << 2;
    int hs = h ^ ((r & 7) << 2);
    *(float4*)(qs + r * 256 + hs) = *(const float4*)(qbase + r * 256 + h);
    *(float4*)(ks + r * 256 + hs) = *(const float4*)(kbase + r * 256 + h);
  }
  __syncthreads();
  const int tq = t >> 4, tk = t & 15;
  const float* q0p = qs + tq * 256;
  const float* q1p = qs + (tq + 16) * 256;   // (tq+16)&7 == tq&7: same swizzle
  const float* k0p = ks + tk * 256;
  const float* k1p = ks + (tk + 16) * 256;
  const int swq = (tq & 7) << 2;
  const int swk = (tk & 7) << 2;
  float a00 = 0.f, a01 = 0.f, a10 = 0.f, a11 = 0.f;
#pragma unroll 2
  for (int h = 0; h < 256; h += 4) {
    float4 w4 = *(const float4*)(wv + h);    // wave-uniform -> s_load
    int hq = h ^ swq, hk = h ^ swk;
    float4 qa = *(const float4*)(q0p + hq);
    float4 qb = *(const float4*)(q1p + hq);
    float4 ka = *(const float4*)(k0p + hk);
    float4 kb = *(const float4*)(k1p + hk);
#define STEP(QA, QB, KA, KB, WJ)                         \
    a00 = __builtin_fmaf(tanh_pre(QA + KA), WJ, a00);    \
    a01 = __builtin_fmaf(tanh_pre(QA + KB), WJ, a01);    \
    a10 = __builtin_fmaf(tanh_pre(QB + KA), WJ, a10);    \
    a11 = __builtin_fmaf(tanh_pre(QB + KB), WJ, a11);
    STEP(qa.x, qb.x, ka.x, kb.x, w4.x)
    STEP(qa.y, qb.y, ka.y, kb.y, w4.y)
    STEP(qa.z, qb.z, ka.z, kb.z, w4.z)
    STEP(qa.w, qb.w, ka.w, kb.w, w4.w)
#undef STEP
  }
  float* s0row = scores + (((b << 8) + q0 + tq) << 8) + k0;
  s0row[tk] = a00;
  s0row[tk + 16] = a01;
  float* s1row = scores + (((b << 8) + q0 + tq + 16) << 8) + k0;
  s1row[tk] = a10;
  s1row[tk + 16] = a11;
}

// ---------- 5) masked softmax over k; emit attn as bf16 hi/lo ----------
__global__ __launch_bounds__(256) void softmax_kernel(
    const float* __restrict__ scores, const int* __restrict__ vlens,
    unsigned short* __restrict__ ahi, unsigned short* __restrict__ alo) {
  int row = (blockIdx.x << 2) + (threadIdx.x >> 6);   // 0..4095
  int lane = threadIdx.x & 63;
  int vl = vlens[row >> 8];
  int kb = lane << 2;
  float4 s4 = *(const float4*)(scores + (row << 8) + kb);
  float s0 = (kb + 0) < vl ? s4.x : -1e6f;
  float s1 = (kb + 1) < vl ? s4.y : -1e6f;
  float s2 = (kb + 2) < vl ? s4.z : -1e6f;
  float s3 = (kb + 3) < vl ? s4.w : -1e6f;
  float mx = fmaxf(fmaxf(s0, s1), fmaxf(s2, s3));
#pragma unroll
  for (int off = 32; off; off >>= 1) mx = fmaxf(mx, __shfl_xor(mx, off, 64));
  float p0 = __expf(s0 - mx), p1 = __expf(s1 - mx);
  float p2 = __expf(s2 - mx), p3 = __expf(s3 - mx);
  float sm = p0 + p1 + p2 + p3;
#pragma unroll
  for (int off = 32; off; off >>= 1) sm += __shfl_xor(sm, off, 64);
  float rs = __builtin_amdgcn_rcpf(sm);
  p0 *= rs; p1 *= rs; p2 *= rs; p3 *= rs;
  unsigned short h0 = f2bf(p0), h1 = f2bf(p1), h2 = f2bf(p2), h3 = f2bf(p3);
  *(ushort4*)(ahi + (row << 8) + kb) = make_ushort4(h0, h1, h2, h3);
  *(ushort4*)(alo + (row << 8) + kb) =
      make_ushort4(f2bf(p0 - bf2f(h0)), f2bf(p1 - bf2f(h1)),
                   f2bf(p2 - bf2f(h2)), f2bf(p3 - bf2f(h3)));
}

// ---------- 6) out[b] = attn[b] (256x256) x values[b] (256x256), bf16 hi/lo MFMA ----------
__global__ __launch_bounds__(256) void av_kernel(
    const unsigned short* __restrict__ ahi, const unsigned short* __restrict__ alo,
    const unsigned short* __restrict__ vhi, const unsigned short* __restrict__ vlo,
    float* __restrict__ out) {
  int wave = threadIdx.x >> 6, lane = threadIdx.x & 63;
  int b = blockIdx.z;
  int m0 = (blockIdx.x * 4 + wave) << 4;
  int n0 = blockIdx.y << 4;
  int r = lane & 15, qd = lane >> 4;
  int base = b << 16;
  int aoff = base + (m0 + r) * 256 + qd * 8;
  int boff = base + (n0 + r) * 256 + qd * 8;
  f32x4 acc = {0.f, 0.f, 0.f, 0.f};
#pragma unroll
  for (int k0 = 0; k0 < 256; k0 += 32) {
    bf16x8 ah = *(const bf16x8*)(ahi + aoff + k0);
    bf16x8 al = *(const bf16x8*)(alo + aoff + k0);
    bf16x8 bh = *(const bf16x8*)(vhi + boff + k0);
    bf16x8 bl = *(const bf16x8*)(vlo + boff + k0);
    acc = __builtin_amdgcn_mfma_f32_16x16x32_bf16(ah, bh, acc, 0, 0, 0);
    acc = __builtin_amdgcn_mfma_f32_16x16x32_bf16(ah, bl, acc, 0, 0, 0);
    acc = __builtin_amdgcn_mfma_f32_16x16x32_bf16(al, bh, acc, 0, 0, 0);
  }
#pragma unroll
  for (int i = 0; i < 4; ++i)
    out[base + (m0 + qd * 4 + i) * 256 + n0 + r] = acc[i];
}

extern "C" void kernel_launch(void* const* d_in, const int* in_sizes, int n_in,
                              void* d_out, int out_size, void* d_ws, size_t ws_size,
                              hipStream_t stream) {
  const float* queries = (const float*)d_in[0];
  const float* keys    = (const float*)d_in[1];
  const float* values  = (const float*)d_in[2];
  const int*   vlens   = (const int*)d_in[3];
  const float* Wq      = (const float*)d_in[4];
  const float* Wk      = (const float*)d_in[5];
  const float* wv      = (const float*)d_in[6];
  float* out = (float*)d_out;
  char* ws = (char*)d_ws;

  // workspace layout (bytes)
  unsigned short* qk_hi = (unsigned short*)(ws + 0);          //  4 MB: 8192x256 bf16
  unsigned short* qk_lo = (unsigned short*)(ws + 4194304);    //  4 MB
  unsigned short* wt_hi = (unsigned short*)(ws + 8388608);    //  256 KB: 2x[n][k]
  unsigned short* wt_lo = (unsigned short*)(ws + 8650752);    //  256 KB
  unsigned short* vt_hi = (unsigned short*)(ws + 8912896);    //  2 MB: 16x[v][k]
  unsigned short* vt_lo = (unsigned short*)(ws + 11010048);   //  2 MB
  float*          qp    = (float*)(ws + 13107200);            //  8 MB: 8192x256 f32 (qp||kp)
  float*          sc    = (float*)(ws + 21495808);            //  4 MB: 16x256x256 f32
  unsigned short* at_hi = (unsigned short*)(ws + 25690112);   //  2 MB
  unsigned short* at_lo = (unsigned short*)(ws + 27787264);   //  2 MB  (end ~29.9 MB)

  cast_qk_kernel<<<2048, 256, 0, stream>>>(queries, keys, qk_hi, qk_lo);
  cast_t_kernel<<<4608, 256, 0, stream>>>(Wq, Wk, values, wt_hi, wt_lo, vt_hi, vt_lo);
  proj_kernel<<<dim3(128, 16), 256, 0, stream>>>(qk_hi, qk_lo, wt_hi, wt_lo, qp);
  scores_kernel<<<dim3(8, 8, 16), 256, 0, stream>>>(qp, qp + 4096 * 256, wv, sc);
  softmax_kernel<<<1024, 256, 0, stream>>>(sc, vlens, at_hi, at_lo);
  av_kernel<<<dim3(4, 16, 16), 256, 0, stream>>>(at_hi, at_lo, vt_hi, vt_lo, out);
}

// Round 2
// 194.834 us; speedup vs baseline: 1.1256x; 1.1256x over previous
//
#include <hip/hip_runtime.h>

// ---------- types ----------
using bf16x8 = __attribute__((ext_vector_type(8))) __bf16;
using f32x4  = __attribute__((ext_vector_type(4))) float;

#define TWO_LOG2E 2.8853900817779268f

__device__ __forceinline__ unsigned short f2bf(float x) {
  unsigned int u = __float_as_uint(x);
  u = (u + 0x7fffu + ((u >> 16) & 1u)) >> 16;   // RNE
  return (unsigned short)u;
}
__device__ __forceinline__ float bf2f(unsigned short h) {
  return __uint_as_float(((unsigned int)h) << 16);
}

// acc += w * tanh(x) where s = 2*log2(e)*x (prescaled).
// tanh(|x|) = (1-u)*P(u), u = 2^(-|s|) = e^(-2|x|), P(u) ~= 1/(1+u) deg-5
// (Chebyshev on [0,1], max err ~4.4e-5). Sign restored via copysign (v_bfi).
// 9 full-rate VALU + 1 trans (exp2's -|s| folds into src modifiers).
__device__ __forceinline__ float tanhw(float s, float w, float acc) {
  float u = __builtin_amdgcn_exp2f(-__builtin_fabsf(s));
  float p = __builtin_fmaf(-0.10765345f, u, 0.42599737f);
  p = __builtin_fmaf(p, u, -0.77778310f);
  p = __builtin_fmaf(p, u, 0.95607530f);
  p = __builtin_fmaf(p, u, -0.99662222f);
  p = __builtin_fmaf(p, u, 0.99995645f);
  float t = __builtin_fmaf(-u, p, p);            // (1-u)*P
  return __builtin_fmaf(__builtin_copysignf(t, s), w, acc);
}

// ---------- 1) cast queries+keys (8192x256) to bf16 hi/lo ----------
__global__ __launch_bounds__(256) void cast_qk_kernel(
    const float* __restrict__ q, const float* __restrict__ k,
    unsigned short* __restrict__ hi, unsigned short* __restrict__ lo) {
  int idx = blockIdx.x * 256 + threadIdx.x;      // float4 id, 0..524287
  int e = idx << 2;
  const float* src = (e < (1 << 20)) ? (q + e) : (k + (e - (1 << 20)));
  float4 v = *(const float4*)src;
  unsigned short h0 = f2bf(v.x), h1 = f2bf(v.y), h2 = f2bf(v.z), h3 = f2bf(v.w);
  *(ushort4*)(hi + e) = make_ushort4(h0, h1, h2, h3);
  *(ushort4*)(lo + e) = make_ushort4(f2bf(v.x - bf2f(h0)), f2bf(v.y - bf2f(h1)),
                                     f2bf(v.z - bf2f(h2)), f2bf(v.w - bf2f(h3)));
}

// ---------- 2) transpose+cast W_q,W_k (->[n][k]) and values (->[b][v][k]) ----------
__global__ __launch_bounds__(256) void cast_t_kernel(
    const float* __restrict__ Wq, const float* __restrict__ Wk, const float* __restrict__ vals,
    unsigned short* __restrict__ wt_hi, unsigned short* __restrict__ wt_lo,
    unsigned short* __restrict__ vt_hi, unsigned short* __restrict__ vt_lo) {
  int idx = blockIdx.x * 256 + threadIdx.x;      // 0..1179647 (18 matrices of 256x256)
  int m = idx >> 16;
  int rem = idx & 65535;
  int r = rem >> 8;    // output row (n or v)
  int c = rem & 255;   // output col (k)
  float x;
  unsigned short *dh, *dl;
  if (m < 2) {
    const float* W = m ? Wk : Wq;
    x = W[c * 256 + r];
    dh = wt_hi + (m << 16) + rem; dl = wt_lo + (m << 16) + rem;
  } else {
    int b = m - 2;
    x = vals[(b << 16) + c * 256 + r];
    dh = vt_hi + (b << 16) + rem; dl = vt_lo + (b << 16) + rem;
  }
  unsigned short h = f2bf(x);
  *dh = h;
  *dl = f2bf(x - bf2f(h));
}

// ---------- 3) projection GEMM: [8192x256] x [256x256] via 16x16x32 bf16 MFMA (hi/lo 3-term)
// Output pre-scaled by 2*log2(e) for the tanh kernel.
__global__ __launch_bounds__(256) void proj_kernel(
    const unsigned short* __restrict__ a_hi, const unsigned short* __restrict__ a_lo,
    const unsigned short* __restrict__ w_hi, const unsigned short* __restrict__ w_lo,
    float* __restrict__ out) {
  int wave = threadIdx.x >> 6, lane = threadIdx.x & 63;
  int m0 = (blockIdx.x * 4 + wave) << 4;   // 0..8176
  int n0 = blockIdx.y << 4;
  int g = m0 >> 12;                        // 0: W_q rows, 1: W_k rows
  int r = lane & 15, qd = lane >> 4;
  int aoff = (m0 + r) * 256 + qd * 8;
  int boff = (g << 16) + (n0 + r) * 256 + qd * 8;
  f32x4 acc = {0.f, 0.f, 0.f, 0.f};
#pragma unroll
  for (int k0 = 0; k0 < 256; k0 += 32) {
    bf16x8 ah = *(const bf16x8*)(a_hi + aoff + k0);
    bf16x8 al = *(const bf16x8*)(a_lo + aoff + k0);
    bf16x8 bh = *(const bf16x8*)(w_hi + boff + k0);
    bf16x8 bl = *(const bf16x8*)(w_lo + boff + k0);
    acc = __builtin_amdgcn_mfma_f32_16x16x32_bf16(ah, bh, acc, 0, 0, 0);
    acc = __builtin_amdgcn_mfma_f32_16x16x32_bf16(ah, bl, acc, 0, 0, 0);
    acc = __builtin_amdgcn_mfma_f32_16x16x32_bf16(al, bh, acc, 0, 0, 0);
  }
#pragma unroll
  for (int i = 0; i < 4; ++i)
    out[(m0 + qd * 4 + i) * 256 + n0 + r] = acc[i] * TWO_LOG2E;
}

// ---------- 4) scores[b][q][k] = sum_h tanh * wv ----------
// 32x32 out-tile / block, 2x2 per thread; h chunked x64 so LDS = 16KB ->
// 8 blocks/CU (32 waves/CU) for trans/VALU cross-wave overlap.
__global__ __launch_bounds__(256, 8) void scores_kernel(
    const float* __restrict__ qp, const float* __restrict__ kp,
    const float* __restrict__ wv, float* __restrict__ scores) {
  __shared__ __align__(16) float qs[32 * 64];
  __shared__ __align__(16) float ks[32 * 64];
  const int t = threadIdx.x;
  const int b = blockIdx.z;
  const int q0 = blockIdx.x << 5;
  const int k0 = blockIdx.y << 5;
  const float* qbase = qp + ((b << 8) + q0) * 256;
  const float* kbase = kp + ((b << 8) + k0) * 256;
  const int tq = t >> 4, tk = t & 15;
  const float* q0p = qs + tq * 64;
  const float* q1p = qs + (tq + 16) * 64;   // (tq+16)&7 == tq&7: same swizzle
  const float* k0p = ks + tk * 64;
  const float* k1p = ks + (tk + 16) * 64;
  const int swq = (tq & 7) << 2;
  const int swk = (tk & 7) << 2;
  float a00 = 0.f, a01 = 0.f, a10 = 0.f, a11 = 0.f;

  for (int hc = 0; hc < 4; ++hc) {
    if (hc) __syncthreads();                // protect previous chunk's reads
    // stage 32x64 q/k chunks, XOR-swizzled (2 float4 per thread per tile)
#pragma unroll
    for (int i = 0; i < 2; ++i) {
      int cid = t + (i << 8);               // 0..511
      int r = cid >> 4;                     // 0..31
      int h4 = (cid & 15) << 2;             // 0..60
      int hs = h4 ^ ((r & 7) << 2);
      int goff = r * 256 + (hc << 6) + h4;
      *(float4*)(qs + r * 64 + hs) = *(const float4*)(qbase + goff);
      *(float4*)(ks + r * 64 + hs) = *(const float4*)(kbase + goff);
    }
    __syncthreads();
#pragma unroll 2
    for (int h = 0; h < 64; h += 4) {
      float4 w4 = *(const float4*)(wv + (hc << 6) + h);  // uniform -> s_load
      int hq = h ^ swq, hk = h ^ swk;
      float4 qa = *(const float4*)(q0p + hq);
      float4 qb = *(const float4*)(q1p + hq);
      float4 ka = *(const float4*)(k0p + hk);
      float4 kb = *(const float4*)(k1p + hk);
#define STEP(QA, QB, KA, KB, WJ)        \
      a00 = tanhw(QA + KA, WJ, a00);    \
      a01 = tanhw(QA + KB, WJ, a01);    \
      a10 = tanhw(QB + KA, WJ, a10);    \
      a11 = tanhw(QB + KB, WJ, a11);
      STEP(qa.x, qb.x, ka.x, kb.x, w4.x)
      STEP(qa.y, qb.y, ka.y, kb.y, w4.y)
      STEP(qa.z, qb.z, ka.z, kb.z, w4.z)
      STEP(qa.w, qb.w, ka.w, kb.w, w4.w)
#undef STEP
    }
  }
  float* s0row = scores + (((b << 8) + q0 + tq) << 8) + k0;
  s0row[tk] = a00;
  s0row[tk + 16] = a01;
  float* s1row = scores + (((b << 8) + q0 + tq + 16) << 8) + k0;
  s1row[tk] = a10;
  s1row[tk + 16] = a11;
}

// ---------- 5) masked softmax over k; emit attn as bf16 hi/lo ----------
__global__ __launch_bounds__(256) void softmax_kernel(
    const float* __restrict__ scores, const int* __restrict__ vlens,
    unsigned short* __restrict__ ahi, unsigned short* __restrict__ alo) {
  int row = (blockIdx.x << 2) + (threadIdx.x >> 6);   // 0..4095
  int lane = threadIdx.x & 63;
  int vl = vlens[row >> 8];
  int kb = lane << 2;
  float4 s4 = *(const float4*)(scores + (row << 8) + kb);
  float s0 = (kb + 0) < vl ? s4.x : -1e6f;
  float s1 = (kb + 1) < vl ? s4.y : -1e6f;
  float s2 = (kb + 2) < vl ? s4.z : -1e6f;
  float s3 = (kb + 3) < vl ? s4.w : -1e6f;
  float mx = fmaxf(fmaxf(s0, s1), fmaxf(s2, s3));
#pragma unroll
  for (int off = 32; off; off >>= 1) mx = fmaxf(mx, __shfl_xor(mx, off, 64));
  float p0 = __expf(s0 - mx), p1 = __expf(s1 - mx);
  float p2 = __expf(s2 - mx), p3 = __expf(s3 - mx);
  float sm = p0 + p1 + p2 + p3;
#pragma unroll
  for (int off = 32; off; off >>= 1) sm += __shfl_xor(sm, off, 64);
  float rs = __builtin_amdgcn_rcpf(sm);
  p0 *= rs; p1 *= rs; p2 *= rs; p3 *= rs;
  unsigned short h0 = f2bf(p0), h1 = f2bf(p1), h2 = f2bf(p2), h3 = f2bf(p3);
  *(ushort4*)(ahi + (row << 8) + kb) = make_ushort4(h0, h1, h2, h3);
  *(ushort4*)(alo + (row << 8) + kb) =
      make_ushort4(f2bf(p0 - bf2f(h0)), f2bf(p1 - bf2f(h1)),
                   f2bf(p2 - bf2f(h2)), f2bf(p3 - bf2f(h3)));
}

// ---------- 6) out[b] = attn[b] (256x256) x values[b] (256x256), bf16 hi/lo MFMA ----------
__global__ __launch_bounds__(256) void av_kernel(
    const unsigned short* __restrict__ ahi, const unsigned short* __restrict__ alo,
    const unsigned short* __restrict__ vhi, const unsigned short* __restrict__ vlo,
    float* __restrict__ out) {
  int wave = threadIdx.x >> 6, lane = threadIdx.x & 63;
  int b = blockIdx.z;
  int m0 = (blockIdx.x * 4 + wave) << 4;
  int n0 = blockIdx.y << 4;
  int r = lane & 15, qd = lane >> 4;
  int base = b << 16;
  int aoff = base + (m0 + r) * 256 + qd * 8;
  int boff = base + (n0 + r) * 256 + qd * 8;
  f32x4 acc = {0.f, 0.f, 0.f, 0.f};
#pragma unroll
  for (int k0 = 0; k0 < 256; k0 += 32) {
    bf16x8 ah = *(const bf16x8*)(ahi + aoff + k0);
    bf16x8 al = *(const bf16x8*)(alo + aoff + k0);
    bf16x8 bh = *(const bf16x8*)(vhi + boff + k0);
    bf16x8 bl = *(const bf16x8*)(vlo + boff + k0);
    acc = __builtin_amdgcn_mfma_f32_16x16x32_bf16(ah, bh, acc, 0, 0, 0);
    acc = __builtin_amdgcn_mfma_f32_16x16x32_bf16(ah, bl, acc, 0, 0, 0);
    acc = __builtin_amdgcn_mfma_f32_16x16x32_bf16(al, bh, acc, 0, 0, 0);
  }
#pragma unroll
  for (int i = 0; i < 4; ++i)
    out[base + (m0 + qd * 4 + i) * 256 + n0 + r] = acc[i];
}

extern "C" void kernel_launch(void* const* d_in, const int* in_sizes, int n_in,
                              void* d_out, int out_size, void* d_ws, size_t ws_size,
                              hipStream_t stream) {
  const float* queries = (const float*)d_in[0];
  const float* keys    = (const float*)d_in[1];
  const float* values  = (const float*)d_in[2];
  const int*   vlens   = (const int*)d_in[3];
  const float* Wq      = (const float*)d_in[4];
  const float* Wk      = (const float*)d_in[5];
  const float* wv      = (const float*)d_in[6];
  float* out = (float*)d_out;
  char* ws = (char*)d_ws;

  // workspace layout (bytes)
  unsigned short* qk_hi = (unsigned short*)(ws + 0);          //  4 MB: 8192x256 bf16
  unsigned short* qk_lo = (unsigned short*)(ws + 4194304);    //  4 MB
  unsigned short* wt_hi = (unsigned short*)(ws + 8388608);    //  256 KB: 2x[n][k]
  unsigned short* wt_lo = (unsigned short*)(ws + 8650752);    //  256 KB
  unsigned short* vt_hi = (unsigned short*)(ws + 8912896);    //  2 MB: 16x[v][k]
  unsigned short* vt_lo = (unsigned short*)(ws + 11010048);   //  2 MB
  float*          qp    = (float*)(ws + 13107200);            //  8 MB: 8192x256 f32 (qp||kp)
  float*          sc    = (float*)(ws + 21495808);            //  4 MB: 16x256x256 f32
  unsigned short* at_hi = (unsigned short*)(ws + 25690112);   //  2 MB
  unsigned short* at_lo = (unsigned short*)(ws + 27787264);   //  2 MB  (end ~29.9 MB)

  cast_qk_kernel<<<2048, 256, 0, stream>>>(queries, keys, qk_hi, qk_lo);
  cast_t_kernel<<<4608, 256, 0, stream>>>(Wq, Wk, values, wt_hi, wt_lo, vt_hi, vt_lo);
  proj_kernel<<<dim3(128, 16), 256, 0, stream>>>(qk_hi, qk_lo, wt_hi, wt_lo, qp);
  scores_kernel<<<dim3(8, 8, 16), 256, 0, stream>>>(qp, qp + 4096 * 256, wv, sc);
  softmax_kernel<<<1024, 256, 0, stream>>>(sc, vlens, at_hi, at_lo);
  av_kernel<<<dim3(4, 16, 16), 256, 0, stream>>>(at_hi, at_lo, vt_hi, vt_lo, out);
}

// Round 3
// 187.386 us; speedup vs baseline: 1.1703x; 1.0397x over previous
//
#include <hip/hip_runtime.h>

// ---------- types ----------
using bf16x8 = __attribute__((ext_vector_type(8))) __bf16;
using f32x4  = __attribute__((ext_vector_type(4))) float;
using f32x2  = __attribute__((ext_vector_type(2))) float;
using f32x4v = __attribute__((ext_vector_type(4))) float;

#define TWO_LOG2E 2.8853900817779268f

__device__ __forceinline__ unsigned short f2bf(float x) {
  unsigned int u = __float_as_uint(x);
  u = (u + 0x7fffu + ((u >> 16) & 1u)) >> 16;   // RNE
  return (unsigned short)u;
}
__device__ __forceinline__ float bf2f(unsigned short h) {
  return __uint_as_float(((unsigned int)h) << 16);
}

__device__ __forceinline__ f32x2 pk_fma(f32x2 a, f32x2 b, f32x2 c) {
  return __builtin_elementwise_fma(a, b, c);
}

// Packed tanh over a float2 of prescaled args (s = 2*log2(e)*x):
// tanh(|x|) = (1-u)*P(u), u = 2^(-|s|), deg-5 poly (validated, err ~4.4e-5).
// Per pair: 8 pk-rate ops + 2 bfi + 2 exp2(trans).
__device__ __forceinline__ f32x2 tanh2(f32x2 s) {
  f32x2 u;
  u.x = __builtin_amdgcn_exp2f(-__builtin_fabsf(s.x));
  u.y = __builtin_amdgcn_exp2f(-__builtin_fabsf(s.y));
  f32x2 p = pk_fma(u, (f32x2)(-0.10765345f), (f32x2)(0.42599737f));
  p = pk_fma(p, u, (f32x2)(-0.77778310f));
  p = pk_fma(p, u, (f32x2)(0.95607530f));
  p = pk_fma(p, u, (f32x2)(-0.99662222f));
  p = pk_fma(p, u, (f32x2)(0.99995645f));
  f32x2 t = pk_fma(-u, p, p);                  // (1-u)*P
  t.x = __builtin_copysignf(t.x, s.x);
  t.y = __builtin_copysignf(t.y, s.y);
  return t;
}

// ---------- 1) fused cast: queries+keys -> bf16 hi/lo ; W_q,W_k,values -> transposed bf16 hi/lo
__global__ __launch_bounds__(256) void cast_all_kernel(
    const float* __restrict__ q, const float* __restrict__ k,
    const float* __restrict__ Wq, const float* __restrict__ Wk, const float* __restrict__ vals,
    unsigned short* __restrict__ hi, unsigned short* __restrict__ lo,
    unsigned short* __restrict__ wt_hi, unsigned short* __restrict__ wt_lo,
    unsigned short* __restrict__ vt_hi, unsigned short* __restrict__ vt_lo) {
  int bid = blockIdx.x;
  if (bid < 2048) {
    int idx = bid * 256 + threadIdx.x;           // float4 id, 0..524287
    int e = idx << 2;
    const float* src = (e < (1 << 20)) ? (q + e) : (k + (e - (1 << 20)));
    float4 v = *(const float4*)src;
    unsigned short h0 = f2bf(v.x), h1 = f2bf(v.y), h2 = f2bf(v.z), h3 = f2bf(v.w);
    *(ushort4*)(hi + e) = make_ushort4(h0, h1, h2, h3);
    *(ushort4*)(lo + e) = make_ushort4(f2bf(v.x - bf2f(h0)), f2bf(v.y - bf2f(h1)),
                                       f2bf(v.z - bf2f(h2)), f2bf(v.w - bf2f(h3)));
  } else {
    int idx = (bid - 2048) * 256 + threadIdx.x;  // 0..1179647 (18 matrices 256x256)
    int m = idx >> 16;
    int rem = idx & 65535;
    int r = rem >> 8;    // output row (n or v)
    int c = rem & 255;   // output col (k)
    float x;
    unsigned short *dh, *dl;
    if (m < 2) {
      const float* W = m ? Wk : Wq;
      x = W[c * 256 + r];
      dh = wt_hi + (m << 16) + rem; dl = wt_lo + (m << 16) + rem;
    } else {
      int b = m - 2;
      x = vals[(b << 16) + c * 256 + r];
      dh = vt_hi + (b << 16) + rem; dl = vt_lo + (b << 16) + rem;
    }
    unsigned short h = f2bf(x);
    *dh = h;
    *dl = f2bf(x - bf2f(h));
  }
}

// ---------- 2) projection GEMM: [8192x256] x [256x256] via 16x16x32 bf16 MFMA (hi/lo 3-term)
__global__ __launch_bounds__(256) void proj_kernel(
    const unsigned short* __restrict__ a_hi, const unsigned short* __restrict__ a_lo,
    const unsigned short* __restrict__ w_hi, const unsigned short* __restrict__ w_lo,
    float* __restrict__ out) {
  int wave = threadIdx.x >> 6, lane = threadIdx.x & 63;
  int m0 = (blockIdx.x * 4 + wave) << 4;   // 0..8176
  int n0 = blockIdx.y << 4;
  int g = m0 >> 12;                        // 0: W_q rows, 1: W_k rows
  int r = lane & 15, qd = lane >> 4;
  int aoff = (m0 + r) * 256 + qd * 8;
  int boff = (g << 16) + (n0 + r) * 256 + qd * 8;
  f32x4 acc = {0.f, 0.f, 0.f, 0.f};
#pragma unroll
  for (int k0 = 0; k0 < 256; k0 += 32) {
    bf16x8 ah = *(const bf16x8*)(a_hi + aoff + k0);
    bf16x8 al = *(const bf16x8*)(a_lo + aoff + k0);
    bf16x8 bh = *(const bf16x8*)(w_hi + boff + k0);
    bf16x8 bl = *(const bf16x8*)(w_lo + boff + k0);
    acc = __builtin_amdgcn_mfma_f32_16x16x32_bf16(ah, bh, acc, 0, 0, 0);
    acc = __builtin_amdgcn_mfma_f32_16x16x32_bf16(ah, bl, acc, 0, 0, 0);
    acc = __builtin_amdgcn_mfma_f32_16x16x32_bf16(al, bh, acc, 0, 0, 0);
  }
#pragma unroll
  for (int i = 0; i < 4; ++i)
    out[(m0 + qd * 4 + i) * 256 + n0 + r] = acc[i] * TWO_LOG2E;
}

// ---------- 3) scores partials: 32q x 32k tile, h split in halves (z>>4), packed fp32 pairs
__global__ __launch_bounds__(256, 8) void scores_kernel(
    const float* __restrict__ qp, const float* __restrict__ kp,
    const float* __restrict__ wv, float* __restrict__ sc0, float* __restrict__ sc1) {
  __shared__ __align__(16) float qs[32 * 72];     // [q][h], padded +8
  __shared__ __align__(16) float ksT[64 * 32];    // [h][k] transposed
  const int t = threadIdx.x;
  const int b = blockIdx.z & 15;
  const int half = blockIdx.z >> 4;
  const int q0 = blockIdx.x << 5;
  const int k0 = blockIdx.y << 5;
  const float* qbase = qp + ((b << 8) + q0) * 256 + (half << 7);
  const float* kbase = kp + ((b << 8) + k0) * 256 + (half << 7);
  const int tq = t >> 4, tk = t & 15;
  const int sr = t >> 3;              // staging row 0..31
  const int shb = (t & 7) << 3;       // staging h base 0..56
  f32x2 a0 = {0.f, 0.f}, a1 = {0.f, 0.f};

  for (int hc = 0; hc < 2; ++hc) {    // two 64-wide h chunks per half
    if (hc) __syncthreads();
    // stage q straight, k transposed
    const float* gq = qbase + sr * 256 + (hc << 6) + shb;
    float4 v0 = *(const float4*)gq;
    float4 v1 = *(const float4*)(gq + 4);
    *(float4*)(qs + sr * 72 + shb) = v0;
    *(float4*)(qs + sr * 72 + shb + 4) = v1;
    const float* gk = kbase + sr * 256 + (hc << 6) + shb;
    float4 w0 = *(const float4*)gk;
    float4 w1 = *(const float4*)(gk + 4);
    ksT[(shb + 0) * 32 + sr] = w0.x;
    ksT[(shb + 1) * 32 + sr] = w0.y;
    ksT[(shb + 2) * 32 + sr] = w0.z;
    ksT[(shb + 3) * 32 + sr] = w0.w;
    ksT[(shb + 4) * 32 + sr] = w1.x;
    ksT[(shb + 5) * 32 + sr] = w1.y;
    ksT[(shb + 6) * 32 + sr] = w1.z;
    ksT[(shb + 7) * 32 + sr] = w1.w;
    __syncthreads();
#pragma unroll 2
    for (int h = 0; h < 64; h += 4) {
      f32x4v qa = *(const f32x4v*)(qs + tq * 72 + h);
      f32x4v qb = *(const f32x4v*)(qs + (tq + 16) * 72 + h);
      f32x4v w4 = *(const f32x4v*)(wv + (half << 7) + (hc << 6) + h);
#pragma unroll
      for (int j = 0; j < 4; ++j) {
        f32x2 kv = *(const f32x2*)(ksT + (h + j) * 32 + (tk << 1));
        f32x2 wj = (f32x2)(w4[j]);
        a0 = pk_fma(tanh2(kv + (f32x2)(qa[j])), wj, a0);
        a1 = pk_fma(tanh2(kv + (f32x2)(qb[j])), wj, a1);
      }
    }
  }
  float* dst = half ? sc1 : sc0;
  *(f32x2*)(dst + (((b << 8) + q0 + tq) << 8) + k0 + (tk << 1)) = a0;
  *(f32x2*)(dst + (((b << 8) + q0 + tq + 16) << 8) + k0 + (tk << 1)) = a1;
}

// ---------- 4) masked softmax over k (sums the two h-partials); emit attn bf16 hi/lo
__global__ __launch_bounds__(256) void softmax_kernel(
    const float* __restrict__ sc0, const float* __restrict__ sc1,
    const int* __restrict__ vlens,
    unsigned short* __restrict__ ahi, unsigned short* __restrict__ alo) {
  int row = (blockIdx.x << 2) + (threadIdx.x >> 6);   // 0..4095
  int lane = threadIdx.x & 63;
  int vl = vlens[row >> 8];
  int kb = lane << 2;
  float4 x0 = *(const float4*)(sc0 + (row << 8) + kb);
  float4 x1 = *(const float4*)(sc1 + (row << 8) + kb);
  float s0 = (kb + 0) < vl ? (x0.x + x1.x) : -1e6f;
  float s1 = (kb + 1) < vl ? (x0.y + x1.y) : -1e6f;
  float s2 = (kb + 2) < vl ? (x0.z + x1.z) : -1e6f;
  float s3 = (kb + 3) < vl ? (x0.w + x1.w) : -1e6f;
  float mx = fmaxf(fmaxf(s0, s1), fmaxf(s2, s3));
#pragma unroll
  for (int off = 32; off; off >>= 1) mx = fmaxf(mx, __shfl_xor(mx, off, 64));
  float p0 = __expf(s0 - mx), p1 = __expf(s1 - mx);
  float p2 = __expf(s2 - mx), p3 = __expf(s3 - mx);
  float sm = p0 + p1 + p2 + p3;
#pragma unroll
  for (int off = 32; off; off >>= 1) sm += __shfl_xor(sm, off, 64);
  float rs = __builtin_amdgcn_rcpf(sm);
  p0 *= rs; p1 *= rs; p2 *= rs; p3 *= rs;
  unsigned short h0 = f2bf(p0), h1 = f2bf(p1), h2 = f2bf(p2), h3 = f2bf(p3);
  *(ushort4*)(ahi + (row << 8) + kb) = make_ushort4(h0, h1, h2, h3);
  *(ushort4*)(alo + (row << 8) + kb) =
      make_ushort4(f2bf(p0 - bf2f(h0)), f2bf(p1 - bf2f(h1)),
                   f2bf(p2 - bf2f(h2)), f2bf(p3 - bf2f(h3)));
}

// ---------- 5) out[b] = attn[b] x values[b], bf16 hi/lo MFMA ----------
__global__ __launch_bounds__(256) void av_kernel(
    const unsigned short* __restrict__ ahi, const unsigned short* __restrict__ alo,
    const unsigned short* __restrict__ vhi, const unsigned short* __restrict__ vlo,
    float* __restrict__ out) {
  int wave = threadIdx.x >> 6, lane = threadIdx.x & 63;
  int b = blockIdx.z;
  int m0 = (blockIdx.x * 4 + wave) << 4;
  int n0 = blockIdx.y << 4;
  int r = lane & 15, qd = lane >> 4;
  int base = b << 16;
  int aoff = base + (m0 + r) * 256 + qd * 8;
  int boff = base + (n0 + r) * 256 + qd * 8;
  f32x4 acc = {0.f, 0.f, 0.f, 0.f};
#pragma unroll
  for (int k0 = 0; k0 < 256; k0 += 32) {
    bf16x8 ah = *(const bf16x8*)(ahi + aoff + k0);
    bf16x8 al = *(const bf16x8*)(alo + aoff + k0);
    bf16x8 bh = *(const bf16x8*)(vhi + boff + k0);
    bf16x8 bl = *(const bf16x8*)(vlo + boff + k0);
    acc = __builtin_amdgcn_mfma_f32_16x16x32_bf16(ah, bh, acc, 0, 0, 0);
    acc = __builtin_amdgcn_mfma_f32_16x16x32_bf16(ah, bl, acc, 0, 0, 0);
    acc = __builtin_amdgcn_mfma_f32_16x16x32_bf16(al, bh, acc, 0, 0, 0);
  }
#pragma unroll
  for (int i = 0; i < 4; ++i)
    out[base + (m0 + qd * 4 + i) * 256 + n0 + r] = acc[i];
}

extern "C" void kernel_launch(void* const* d_in, const int* in_sizes, int n_in,
                              void* d_out, int out_size, void* d_ws, size_t ws_size,
                              hipStream_t stream) {
  const float* queries = (const float*)d_in[0];
  const float* keys    = (const float*)d_in[1];
  const float* values  = (const float*)d_in[2];
  const int*   vlens   = (const int*)d_in[3];
  const float* Wq      = (const float*)d_in[4];
  const float* Wk      = (const float*)d_in[5];
  const float* wv      = (const float*)d_in[6];
  float* out = (float*)d_out;
  char* ws = (char*)d_ws;

  // workspace layout (bytes); sc1 aliases qk_hi (dead after proj)
  unsigned short* qk_hi = (unsigned short*)(ws + 0);          //  4 MB: 8192x256 bf16
  unsigned short* qk_lo = (unsigned short*)(ws + 4194304);    //  4 MB
  unsigned short* wt_hi = (unsigned short*)(ws + 8388608);    //  256 KB
  unsigned short* wt_lo = (unsigned short*)(ws + 8650752);    //  256 KB
  unsigned short* vt_hi = (unsigned short*)(ws + 8912896);    //  2 MB
  unsigned short* vt_lo = (unsigned short*)(ws + 11010048);   //  2 MB
  float*          qp    = (float*)(ws + 13107200);            //  8 MB (qp||kp)
  float*          sc0   = (float*)(ws + 21495808);            //  4 MB
  float*          sc1   = (float*)(ws + 0);                   //  4 MB (aliases qk_hi/lo)
  unsigned short* at_hi = (unsigned short*)(ws + 25690112);   //  2 MB
  unsigned short* at_lo = (unsigned short*)(ws + 27787264);   //  2 MB  (end ~29.9 MB)

  cast_all_kernel<<<6656, 256, 0, stream>>>(queries, keys, Wq, Wk, values,
                                            qk_hi, qk_lo, wt_hi, wt_lo, vt_hi, vt_lo);
  proj_kernel<<<dim3(128, 16), 256, 0, stream>>>(qk_hi, qk_lo, wt_hi, wt_lo, qp);
  scores_kernel<<<dim3(8, 8, 32), 256, 0, stream>>>(qp, qp + 4096 * 256, wv, sc0, sc1);
  softmax_kernel<<<1024, 256, 0, stream>>>(sc0, sc1, vlens, at_hi, at_lo);
  av_kernel<<<dim3(4, 16, 16), 256, 0, stream>>>(at_hi, at_lo, vt_hi, vt_lo, out);
}

// Round 4
// 169.741 us; speedup vs baseline: 1.2919x; 1.1040x over previous
//
#include <hip/hip_runtime.h>

// ---------- types ----------
using bf16x8 = __attribute__((ext_vector_type(8))) __bf16;
using f32x4  = __attribute__((ext_vector_type(4))) float;
using f32x2  = __attribute__((ext_vector_type(2))) float;

#define LOG2E 1.4426950408889634f

__device__ __forceinline__ unsigned short f2bf(float x) {
  unsigned int u = __float_as_uint(x);
  u = (u + 0x7fffu + ((u >> 16) & 1u)) >> 16;   // RNE
  return (unsigned short)u;
}
__device__ __forceinline__ float bf2f(unsigned short h) {
  return __uint_as_float(((unsigned int)h) << 16);
}
__device__ __forceinline__ f32x2 pk_fma(f32x2 a, f32x2 b, f32x2 c) {
  return __builtin_elementwise_fma(a, b, c);
}
// packed reciprocal: bit-trick seed + 2 Newton steps, no trans ops.
// d in [2^-110, 2^112] (guaranteed by the ±55 clamp in proj) -> rel err ~1e-5.
__device__ __forceinline__ f32x2 nrrcp2(f32x2 d) {
  f32x2 r;
  r.x = __uint_as_float(0x7EF311C3u - __float_as_uint(d.x));
  r.y = __uint_as_float(0x7EF311C3u - __float_as_uint(d.y));
  r = r * pk_fma(-d, r, (f32x2)(2.0f));
  r = r * pk_fma(-d, r, (f32x2)(2.0f));
  return r;
}

// ---------- 1) tiled transpose+cast: W_q,W_k,values -> [n][k] bf16 hi/lo ----------
// 18 matrices of 256x256, 32x32 tiles through LDS; coalesced both sides.
__global__ __launch_bounds__(256) void tcast_kernel(
    const float* __restrict__ Wq, const float* __restrict__ Wk,
    const float* __restrict__ vals,
    unsigned short* __restrict__ wt_hi, unsigned short* __restrict__ wt_lo,
    unsigned short* __restrict__ vt_hi, unsigned short* __restrict__ vt_lo) {
  __shared__ float tile[32][33];
  int m = blockIdx.x >> 6;                 // matrix 0..17
  int ts = blockIdx.x & 63;
  int R0 = (ts >> 3) << 5, C0 = (ts & 7) << 5;
  const float* src = (m == 0) ? Wq : (m == 1) ? Wk : (vals + ((m - 2) << 16));
  int r = threadIdx.x >> 3, c4 = (threadIdx.x & 7) << 2;
  float4 v = *(const float4*)(src + (R0 + r) * 256 + C0 + c4);
  tile[r][c4] = v.x; tile[r][c4 + 1] = v.y; tile[r][c4 + 2] = v.z; tile[r][c4 + 3] = v.w;
  __syncthreads();
  float o0 = tile[c4 + 0][r], o1 = tile[c4 + 1][r];
  float o2 = tile[c4 + 2][r], o3 = tile[c4 + 3][r];
  unsigned short h0 = f2bf(o0), h1 = f2bf(o1), h2 = f2bf(o2), h3 = f2bf(o3);
  int base = ((m < 2) ? (m << 16) : ((m - 2) << 16)) + (C0 + r) * 256 + R0 + c4;
  unsigned short* dh = (m < 2) ? wt_hi : vt_hi;
  unsigned short* dl = (m < 2) ? wt_lo : vt_lo;
  *(ushort4*)(dh + base) = make_ushort4(h0, h1, h2, h3);
  *(ushort4*)(dl + base) = make_ushort4(f2bf(o0 - bf2f(h0)), f2bf(o1 - bf2f(h1)),
                                        f2bf(o2 - bf2f(h2)), f2bf(o3 - bf2f(h3)));
}

// ---------- 2) projection GEMM + exp epilogue ----------
// [8192x256] x [256x256], A read fp32 direct from q/k, split hi/lo in regs,
// 3-term bf16 MFMA. Epilogue: Eq = 2^clamp(log2e*proj, +-55), Eqi = 2^-l.
__global__ __launch_bounds__(256) void proj_kernel(
    const float* __restrict__ q, const float* __restrict__ kk,
    const unsigned short* __restrict__ w_hi, const unsigned short* __restrict__ w_lo,
    float* __restrict__ Eq, float* __restrict__ Eqi) {
  int wave = threadIdx.x >> 6, lane = threadIdx.x & 63;
  int m0 = (blockIdx.x * 4 + wave) << 4;   // 0..8176
  int g = m0 >> 12;                        // 0: q rows / W_q, 1: k rows / W_k
  int r = lane & 15, qd = lane >> 4;
  int row = m0 + r;
  const float* A = (g == 0) ? (q + row * 256) : (kk + (row - 4096) * 256);
  bf16x8 ah[8], al[8];
#pragma unroll
  for (int s = 0; s < 8; ++s) {
    const float* p = A + qd * 8 + s * 32;
    float4 f0 = *(const float4*)p;
    float4 f1 = *(const float4*)(p + 4);
    float fv[8] = {f0.x, f0.y, f0.z, f0.w, f1.x, f1.y, f1.z, f1.w};
#pragma unroll
    for (int j = 0; j < 8; ++j) {
      __bf16 h = (__bf16)fv[j];
      ah[s][j] = h;
      al[s][j] = (__bf16)(fv[j] - (float)h);
    }
  }
  int nb = blockIdx.y << 6;
#pragma unroll
  for (int t = 0; t < 4; ++t) {
    int n0 = nb + (t << 4);
    int boff = (g << 16) + (n0 + r) * 256 + qd * 8;
    f32x4 acc = {0.f, 0.f, 0.f, 0.f};
#pragma unroll
    for (int s = 0; s < 8; ++s) {
      bf16x8 bh = *(const bf16x8*)(w_hi + boff + s * 32);
      bf16x8 bl = *(const bf16x8*)(w_lo + boff + s * 32);
      acc = __builtin_amdgcn_mfma_f32_16x16x32_bf16(ah[s], bh, acc, 0, 0, 0);
      acc = __builtin_amdgcn_mfma_f32_16x16x32_bf16(ah[s], bl, acc, 0, 0, 0);
      acc = __builtin_amdgcn_mfma_f32_16x16x32_bf16(al[s], bh, acc, 0, 0, 0);
    }
#pragma unroll
    for (int i = 0; i < 4; ++i) {
      float l = acc[i] * LOG2E;
      l = fminf(fmaxf(l, -55.f), 55.f);
      int idx = (m0 + qd * 4 + i) * 256 + n0 + r;
      Eq[idx]  = __builtin_amdgcn_exp2f(l);
      Eqi[idx] = __builtin_amdgcn_exp2f(-l);
    }
  }
}

// ---------- 3) scores[b][q][k] = sum_h w_h * (E-1/E)/(E+1/E), E = Eq*Ek ----------
// Zero transcendentals in the inner loop; all packed fp32.
__global__ __launch_bounds__(256, 4) void scores_kernel(
    const float* __restrict__ E, const float* __restrict__ Ei,
    const float* __restrict__ wv, float* __restrict__ sc) {
  __shared__ __align__(16) float eqs[32 * 72];
  __shared__ __align__(16) float eqis[32 * 72];
  __shared__ __align__(16) float ekT[64 * 34];   // [h][k], pad 34: b64-aligned reads
  __shared__ __align__(16) float ekiT[64 * 34];
  const int t = threadIdx.x;
  const int b = blockIdx.z;
  const int q0 = blockIdx.x << 5;
  const int k0 = blockIdx.y << 5;
  const int qrow = (b << 8) + q0;
  const int krow = (b << 8) + k0;
  const int tq = t >> 4, tk = t & 15;
  const int sr = t >> 3, shb = (t & 7) << 3;
  f32x2 a0 = {0.f, 0.f}, a1 = {0.f, 0.f};

  for (int hc = 0; hc < 4; ++hc) {
    if (hc) __syncthreads();
    const float* gq  = E  + (qrow + sr) * 256 + (hc << 6) + shb;
    const float* gqi = Ei + (qrow + sr) * 256 + (hc << 6) + shb;
    *(float4*)(eqs + sr * 72 + shb)      = *(const float4*)gq;
    *(float4*)(eqs + sr * 72 + shb + 4)  = *(const float4*)(gq + 4);
    *(float4*)(eqis + sr * 72 + shb)     = *(const float4*)gqi;
    *(float4*)(eqis + sr * 72 + shb + 4) = *(const float4*)(gqi + 4);
    const float* gk  = E  + (1 << 20) + (krow + sr) * 256 + (hc << 6) + shb;
    const float* gki = Ei + (1 << 20) + (krow + sr) * 256 + (hc << 6) + shb;
    float4 w0 = *(const float4*)gk,  w1 = *(const float4*)(gk + 4);
    float4 x0 = *(const float4*)gki, x1 = *(const float4*)(gki + 4);
    ekT[(shb + 0) * 34 + sr] = w0.x;  ekT[(shb + 1) * 34 + sr] = w0.y;
    ekT[(shb + 2) * 34 + sr] = w0.z;  ekT[(shb + 3) * 34 + sr] = w0.w;
    ekT[(shb + 4) * 34 + sr] = w1.x;  ekT[(shb + 5) * 34 + sr] = w1.y;
    ekT[(shb + 6) * 34 + sr] = w1.z;  ekT[(shb + 7) * 34 + sr] = w1.w;
    ekiT[(shb + 0) * 34 + sr] = x0.x; ekiT[(shb + 1) * 34 + sr] = x0.y;
    ekiT[(shb + 2) * 34 + sr] = x0.z; ekiT[(shb + 3) * 34 + sr] = x0.w;
    ekiT[(shb + 4) * 34 + sr] = x1.x; ekiT[(shb + 5) * 34 + sr] = x1.y;
    ekiT[(shb + 6) * 34 + sr] = x1.z; ekiT[(shb + 7) * 34 + sr] = x1.w;
    __syncthreads();
#pragma unroll 2
    for (int h = 0; h < 64; h += 4) {
      f32x4 eqa  = *(const f32x4*)(eqs  + tq * 72 + h);
      f32x4 eqia = *(const f32x4*)(eqis + tq * 72 + h);
      f32x4 eqb  = *(const f32x4*)(eqs  + (tq + 16) * 72 + h);
      f32x4 eqib = *(const f32x4*)(eqis + (tq + 16) * 72 + h);
      f32x4 w4 = *(const f32x4*)(wv + (hc << 6) + h);
#pragma unroll
      for (int j = 0; j < 4; ++j) {
        f32x2 ek2  = *(const f32x2*)(ekT  + (h + j) * 34 + (tk << 1));
        f32x2 eki2 = *(const f32x2*)(ekiT + (h + j) * 34 + (tk << 1));
        f32x2 wj = (f32x2)(w4[j]);
        {
          f32x2 ei  = eki2 * (f32x2)(eqia[j]);
          f32x2 den = pk_fma(ek2, (f32x2)(eqa[j]), ei);
          f32x2 num = pk_fma(ek2, (f32x2)(eqa[j]), -ei);
          a0 = pk_fma(num * nrrcp2(den), wj, a0);
        }
        {
          f32x2 ei  = eki2 * (f32x2)(eqib[j]);
          f32x2 den = pk_fma(ek2, (f32x2)(eqb[j]), ei);
          f32x2 num = pk_fma(ek2, (f32x2)(eqb[j]), -ei);
          a1 = pk_fma(num * nrrcp2(den), wj, a1);
        }
      }
    }
  }
  *(f32x2*)(sc + ((qrow + tq) << 8) + k0 + (tk << 1)) = a0;
  *(f32x2*)(sc + ((qrow + tq + 16) << 8) + k0 + (tk << 1)) = a1;
}

// ---------- 4) masked softmax over k; emit attn bf16 hi/lo ----------
__global__ __launch_bounds__(256) void softmax_kernel(
    const float* __restrict__ sc, const int* __restrict__ vlens,
    unsigned short* __restrict__ ahi, unsigned short* __restrict__ alo) {
  int row = (blockIdx.x << 2) + (threadIdx.x >> 6);   // 0..4095
  int lane = threadIdx.x & 63;
  int vl = vlens[row >> 8];
  int kb = lane << 2;
  float4 s4 = *(const float4*)(sc + (row << 8) + kb);
  float s0 = (kb + 0) < vl ? s4.x : -1e6f;
  float s1 = (kb + 1) < vl ? s4.y : -1e6f;
  float s2 = (kb + 2) < vl ? s4.z : -1e6f;
  float s3 = (kb + 3) < vl ? s4.w : -1e6f;
  float mx = fmaxf(fmaxf(s0, s1), fmaxf(s2, s3));
#pragma unroll
  for (int off = 32; off; off >>= 1) mx = fmaxf(mx, __shfl_xor(mx, off, 64));
  float p0 = __expf(s0 - mx), p1 = __expf(s1 - mx);
  float p2 = __expf(s2 - mx), p3 = __expf(s3 - mx);
  float sm = p0 + p1 + p2 + p3;
#pragma unroll
  for (int off = 32; off; off >>= 1) sm += __shfl_xor(sm, off, 64);
  float rs = __builtin_amdgcn_rcpf(sm);
  p0 *= rs; p1 *= rs; p2 *= rs; p3 *= rs;
  unsigned short h0 = f2bf(p0), h1 = f2bf(p1), h2 = f2bf(p2), h3 = f2bf(p3);
  *(ushort4*)(ahi + (row << 8) + kb) = make_ushort4(h0, h1, h2, h3);
  *(ushort4*)(alo + (row << 8) + kb) =
      make_ushort4(f2bf(p0 - bf2f(h0)), f2bf(p1 - bf2f(h1)),
                   f2bf(p2 - bf2f(h2)), f2bf(p3 - bf2f(h3)));
}

// ---------- 5) out[b] = attn[b] x values[b], bf16 hi/lo MFMA ----------
__global__ __launch_bounds__(256) void av_kernel(
    const unsigned short* __restrict__ ahi, const unsigned short* __restrict__ alo,
    const unsigned short* __restrict__ vhi, const unsigned short* __restrict__ vlo,
    float* __restrict__ out) {
  int wave = threadIdx.x >> 6, lane = threadIdx.x & 63;
  int b = blockIdx.z;
  int m0 = (blockIdx.x * 4 + wave) << 4;
  int n0 = blockIdx.y << 4;
  int r = lane & 15, qd = lane >> 4;
  int base = b << 16;
  int aoff = base + (m0 + r) * 256 + qd * 8;
  int boff = base + (n0 + r) * 256 + qd * 8;
  f32x4 acc = {0.f, 0.f, 0.f, 0.f};
#pragma unroll
  for (int k0 = 0; k0 < 256; k0 += 32) {
    bf16x8 ah = *(const bf16x8*)(ahi + aoff + k0);
    bf16x8 al = *(const bf16x8*)(alo + aoff + k0);
    bf16x8 bh = *(const bf16x8*)(vhi + boff + k0);
    bf16x8 bl = *(const bf16x8*)(vlo + boff + k0);
    acc = __builtin_amdgcn_mfma_f32_16x16x32_bf16(ah, bh, acc, 0, 0, 0);
    acc = __builtin_amdgcn_mfma_f32_16x16x32_bf16(ah, bl, acc, 0, 0, 0);
    acc = __builtin_amdgcn_mfma_f32_16x16x32_bf16(al, bh, acc, 0, 0, 0);
  }
#pragma unroll
  for (int i = 0; i < 4; ++i)
    out[base + (m0 + qd * 4 + i) * 256 + n0 + r] = acc[i];
}

extern "C" void kernel_launch(void* const* d_in, const int* in_sizes, int n_in,
                              void* d_out, int out_size, void* d_ws, size_t ws_size,
                              hipStream_t stream) {
  const float* queries = (const float*)d_in[0];
  const float* keys    = (const float*)d_in[1];
  const float* values  = (const float*)d_in[2];
  const int*   vlens   = (const int*)d_in[3];
  const float* Wq      = (const float*)d_in[4];
  const float* Wk      = (const float*)d_in[5];
  const float* wv      = (const float*)d_in[6];
  float* out = (float*)d_out;
  char* ws = (char*)d_ws;

  // workspace layout (bytes), total 29.9 MB
  unsigned short* wt_hi = (unsigned short*)(ws + 0);          // 256 KB
  unsigned short* wt_lo = (unsigned short*)(ws + 262144);     // 256 KB
  unsigned short* vt_hi = (unsigned short*)(ws + 524288);     //   2 MB
  unsigned short* vt_lo = (unsigned short*)(ws + 2621440);    //   2 MB
  float*          Eq    = (float*)(ws + 4718592);             //   8 MB (q rows || k rows)
  float*          Eqi   = (float*)(ws + 13107200);            //   8 MB
  float*          sc    = (float*)(ws + 21495808);            //   4 MB
  unsigned short* at_hi = (unsigned short*)(ws + 25690112);   //   2 MB
  unsigned short* at_lo = (unsigned short*)(ws + 27787264);   //   2 MB -> end 29884416

  tcast_kernel<<<1152, 256, 0, stream>>>(Wq, Wk, values, wt_hi, wt_lo, vt_hi, vt_lo);
  proj_kernel<<<dim3(128, 4), 256, 0, stream>>>(queries, keys, wt_hi, wt_lo, Eq, Eqi);
  scores_kernel<<<dim3(8, 8, 16), 256, 0, stream>>>(Eq, Eqi, wv, sc);
  softmax_kernel<<<1024, 256, 0, stream>>>(sc, vlens, at_hi, at_lo);
  av_kernel<<<dim3(4, 16, 16), 256, 0, stream>>>(at_hi, at_lo, vt_hi, vt_lo, out);
}

// Round 5
// 138.681 us; speedup vs baseline: 1.5813x; 1.2240x over previous
//
#include <hip/hip_runtime.h>

// ---------- types ----------
using bf16x8 = __attribute__((ext_vector_type(8))) __bf16;
using f32x4  = __attribute__((ext_vector_type(4))) float;
using f32x2  = __attribute__((ext_vector_type(2))) float;
using us8    = __attribute__((ext_vector_type(8))) unsigned short;

#define TWO_LOG2E 2.8853900817779268f
#define LOG2E 1.4426950408889634f

__device__ __forceinline__ unsigned short f2bf(float x) {
  unsigned int u = __float_as_uint(x);
  u = (u + 0x7fffu + ((u >> 16) & 1u)) >> 16;   // RNE
  return (unsigned short)u;
}
__device__ __forceinline__ float bf2f(unsigned short h) {
  return __uint_as_float(((unsigned int)h) << 16);
}
__device__ __forceinline__ f32x2 pk_fma(f32x2 a, f32x2 b, f32x2 c) {
  return __builtin_elementwise_fma(a, b, c);
}

// ---------- 1) tiled transpose+cast W/V + wv prologue ----------
__global__ __launch_bounds__(256) void tcast_kernel(
    const float* __restrict__ Wq, const float* __restrict__ Wk,
    const float* __restrict__ vals, const float* __restrict__ wv,
    unsigned short* __restrict__ wt_hi, unsigned short* __restrict__ wt_lo,
    unsigned short* __restrict__ vt_hi, unsigned short* __restrict__ vt_lo,
    float* __restrict__ wv2, float* __restrict__ Wsum) {
  if (blockIdx.x == 0) {
    int t = threadIdx.x;
    wv2[t] = -2.0f * wv[t];                       // folded weight for scores
    if (t < 64) {
      float s = wv[t] + wv[t + 64] + wv[t + 128] + wv[t + 192];
#pragma unroll
      for (int off = 1; off < 64; off <<= 1) s += __shfl_xor(s, off, 64);
      if (t == 0) Wsum[0] = s;
    }
  }
  __shared__ float tile[32][33];
  int m = blockIdx.x >> 6;                 // matrix 0..17
  int ts = blockIdx.x & 63;
  int R0 = (ts >> 3) << 5, C0 = (ts & 7) << 5;
  const float* src = (m == 0) ? Wq : (m == 1) ? Wk : (vals + ((m - 2) << 16));
  int r = threadIdx.x >> 3, c4 = (threadIdx.x & 7) << 2;
  float4 v = *(const float4*)(src + (R0 + r) * 256 + C0 + c4);
  tile[r][c4] = v.x; tile[r][c4 + 1] = v.y; tile[r][c4 + 2] = v.z; tile[r][c4 + 3] = v.w;
  __syncthreads();
  float o0 = tile[c4 + 0][r], o1 = tile[c4 + 1][r];
  float o2 = tile[c4 + 2][r], o3 = tile[c4 + 3][r];
  unsigned short h0 = f2bf(o0), h1 = f2bf(o1), h2 = f2bf(o2), h3 = f2bf(o3);
  int base = ((m < 2) ? (m << 16) : ((m - 2) << 16)) + (C0 + r) * 256 + R0 + c4;
  unsigned short* dh = (m < 2) ? wt_hi : vt_hi;
  unsigned short* dl = (m < 2) ? wt_lo : vt_lo;
  *(ushort4*)(dh + base) = make_ushort4(h0, h1, h2, h3);
  *(ushort4*)(dl + base) = make_ushort4(f2bf(o0 - bf2f(h0)), f2bf(o1 - bf2f(h1)),
                                        f2bf(o2 - bf2f(h2)), f2bf(o3 - bf2f(h3)));
}

// ---------- 2) projection GEMM + R = e^{2x} epilogue ----------
// grid (256,4): block = 2 m-tiles x 64 n-cols; wave: 1 m-tile, 2 n-tiles.
__global__ __launch_bounds__(256, 4) void proj_kernel(
    const float* __restrict__ q, const float* __restrict__ kk,
    const unsigned short* __restrict__ w_hi, const unsigned short* __restrict__ w_lo,
    float* __restrict__ R) {
  int wave = threadIdx.x >> 6, lane = threadIdx.x & 63;
  int mt = (blockIdx.x << 1) + (wave & 1);   // m-tile 0..511
  int m0 = mt << 4;
  int g = mt >> 8;                           // 0: q rows / W_q, 1: k rows / W_k
  int r = lane & 15, qd = lane >> 4;
  int row = m0 + r;
  const float* A = (g == 0) ? (q + row * 256) : (kk + (row - 4096) * 256);
  bf16x8 ah[8], al[8];
#pragma unroll
  for (int s = 0; s < 8; ++s) {
    const float* p = A + qd * 8 + s * 32;
    float4 f0 = *(const float4*)p;
    float4 f1 = *(const float4*)(p + 4);
    float fv[8] = {f0.x, f0.y, f0.z, f0.w, f1.x, f1.y, f1.z, f1.w};
#pragma unroll
    for (int j = 0; j < 8; ++j) {
      __bf16 h = (__bf16)fv[j];
      ah[s][j] = h;
      al[s][j] = (__bf16)(fv[j] - (float)h);
    }
  }
  int nbase = (blockIdx.y << 6) + ((wave >> 1) << 5);
#pragma unroll
  for (int tI = 0; tI < 2; ++tI) {
    int n0 = nbase + (tI << 4);
    int boff = (g << 16) + (n0 + r) * 256 + qd * 8;
    f32x4 acc = {0.f, 0.f, 0.f, 0.f};
#pragma unroll
    for (int s = 0; s < 8; ++s) {
      bf16x8 bh = *(const bf16x8*)(w_hi + boff + s * 32);
      bf16x8 bl = *(const bf16x8*)(w_lo + boff + s * 32);
      acc = __builtin_amdgcn_mfma_f32_16x16x32_bf16(ah[s], bh, acc, 0, 0, 0);
      acc = __builtin_amdgcn_mfma_f32_16x16x32_bf16(ah[s], bl, acc, 0, 0, 0);
      acc = __builtin_amdgcn_mfma_f32_16x16x32_bf16(al[s], bh, acc, 0, 0, 0);
    }
#pragma unroll
    for (int i = 0; i < 4; ++i) {
      float l = acc[i] * TWO_LOG2E;                 // log2(e^{2x})
      l = fminf(fmaxf(l, -27.f), 27.f);             // |x|<9.35 never hit for N(0,1)
      R[(m0 + qd * 4 + i) * 256 + n0 + r] = __builtin_amdgcn_exp2f(l);
    }
  }
}

// ---------- 3) scores[b][q][k] = Wsum + sum_h (-2 w_h)/(1 + Rq*Rk) ----------
// 4 packed + 2 int ops per k-pair; zero transcendentals.
__global__ __launch_bounds__(256, 8) void scores_kernel(
    const float* __restrict__ R, const float* __restrict__ wv2,
    const float* __restrict__ Wsum, float* __restrict__ sc) {
  __shared__ __align__(16) float rqs[32 * 76];   // [q][h], pad 76 (2-way max)
  __shared__ __align__(16) float rkT[64 * 34];   // [h][k], pad 34 (b64-aligned)
  const int t = threadIdx.x;
  const int b = blockIdx.z;
  const int q0 = blockIdx.x << 5;
  const int k0 = blockIdx.y << 5;
  const int qrow = (b << 8) + q0;
  const int krow = (b << 8) + k0;
  const int tq = t >> 4, tk = t & 15;
  const int sr = t >> 3, shb = (t & 7) << 3;
  f32x2 a0 = {0.f, 0.f}, a1 = {0.f, 0.f};

  for (int hc = 0; hc < 4; ++hc) {
    if (hc) __syncthreads();
    const float* gq = R + (qrow + sr) * 256 + (hc << 6) + shb;
    *(float4*)(rqs + sr * 76 + shb)     = *(const float4*)gq;
    *(float4*)(rqs + sr * 76 + shb + 4) = *(const float4*)(gq + 4);
    const float* gk = R + (1 << 20) + (krow + sr) * 256 + (hc << 6) + shb;
    float4 w0 = *(const float4*)gk, w1 = *(const float4*)(gk + 4);
    rkT[(shb + 0) * 34 + sr] = w0.x;  rkT[(shb + 1) * 34 + sr] = w0.y;
    rkT[(shb + 2) * 34 + sr] = w0.z;  rkT[(shb + 3) * 34 + sr] = w0.w;
    rkT[(shb + 4) * 34 + sr] = w1.x;  rkT[(shb + 5) * 34 + sr] = w1.y;
    rkT[(shb + 6) * 34 + sr] = w1.z;  rkT[(shb + 7) * 34 + sr] = w1.w;
    __syncthreads();
#pragma unroll 2
    for (int h = 0; h < 64; h += 4) {
      f32x4 qa = *(const f32x4*)(rqs + tq * 76 + h);
      f32x4 qb = *(const f32x4*)(rqs + (tq + 16) * 76 + h);
      f32x4 wm = *(const f32x4*)(wv2 + (hc << 6) + h);
#pragma unroll
      for (int j = 0; j < 4; ++j) {
        f32x2 rk = *(const f32x2*)(rkT + (h + j) * 34 + (tk << 1));
        f32x2 d0 = pk_fma(rk, (f32x2)(qa[j]), (f32x2)(1.0f));
        f32x2 d1 = pk_fma(rk, (f32x2)(qb[j]), (f32x2)(1.0f));
        f32x2 r0, r1;
        r0.x = __uint_as_float(0x7EF311C3u - __float_as_uint(d0.x));
        r0.y = __uint_as_float(0x7EF311C3u - __float_as_uint(d0.y));
        r1.x = __uint_as_float(0x7EF311C3u - __float_as_uint(d1.x));
        r1.y = __uint_as_float(0x7EF311C3u - __float_as_uint(d1.y));
        r0 = r0 * pk_fma(-d0, r0, (f32x2)(2.0f));   // 1 Newton, rel err <=1.2e-3
        r1 = r1 * pk_fma(-d1, r1, (f32x2)(2.0f));
        f32x2 wj = (f32x2)(wm[j]);
        a0 = pk_fma(r0, wj, a0);
        a1 = pk_fma(r1, wj, a1);
      }
    }
  }
  float ws = Wsum[0];
  a0 += (f32x2)(ws);
  a1 += (f32x2)(ws);
  *(f32x2*)(sc + ((qrow + tq) << 8) + k0 + (tk << 1)) = a0;
  *(f32x2*)(sc + ((qrow + tq + 16) << 8) + k0 + (tk << 1)) = a1;
}

// ---------- 4) fused masked-softmax + AV ----------
// block = 16 q-rows x 128 v-cols; softmax computed in-block, attn staged
// to LDS as bf16 hi/lo, then 16x16x32 MFMA against transposed values.
__global__ __launch_bounds__(256) void av_fused_kernel(
    const float* __restrict__ sc, const int* __restrict__ vlens,
    const unsigned short* __restrict__ vhi, const unsigned short* __restrict__ vlo,
    float* __restrict__ out) {
  __shared__ __align__(16) unsigned short athi[16 * 264];
  __shared__ __align__(16) unsigned short atlo[16 * 264];
  const int wave = threadIdx.x >> 6, lane = threadIdx.x & 63;
  const int m0 = blockIdx.x << 4;
  const int nh = blockIdx.y;             // n-half 0/1
  const int b = blockIdx.z;
  const int vl = vlens[b];

  // --- softmax: wave handles rows wave*4 + (lane&3); lane holds 16 cols ---
  {
    int row = (wave << 2) + (lane & 3);
    int c0 = (lane >> 2) << 4;
    const float* srow = sc + ((b << 8) + m0 + row) * 256 + c0;
    float4 x0 = *(const float4*)(srow);
    float4 x1 = *(const float4*)(srow + 4);
    float4 x2 = *(const float4*)(srow + 8);
    float4 x3 = *(const float4*)(srow + 12);
    float p[16] = {x0.x, x0.y, x0.z, x0.w, x1.x, x1.y, x1.z, x1.w,
                   x2.x, x2.y, x2.z, x2.w, x3.x, x3.y, x3.z, x3.w};
#pragma unroll
    for (int i = 0; i < 16; ++i)
      if (c0 + i >= vl) p[i] = -1e6f;
    float mx = p[0];
#pragma unroll
    for (int i = 1; i < 16; ++i) mx = fmaxf(mx, p[i]);
#pragma unroll
    for (int off = 4; off <= 32; off <<= 1) mx = fmaxf(mx, __shfl_xor(mx, off, 64));
    float sm = 0.f;
#pragma unroll
    for (int i = 0; i < 16; ++i) {
      p[i] = __builtin_amdgcn_exp2f((p[i] - mx) * LOG2E);
      sm += p[i];
    }
#pragma unroll
    for (int off = 4; off <= 32; off <<= 1) sm += __shfl_xor(sm, off, 64);
    float rs = __builtin_amdgcn_rcpf(sm);
    us8 vh[2], vlo2[2];
#pragma unroll
    for (int i = 0; i < 16; ++i) {
      float sv = p[i] * rs;
      unsigned short h = f2bf(sv);
      vh[i >> 3][i & 7] = h;
      vlo2[i >> 3][i & 7] = f2bf(sv - bf2f(h));
    }
    *(us8*)(athi + row * 264 + c0)     = vh[0];
    *(us8*)(athi + row * 264 + c0 + 8) = vh[1];
    *(us8*)(atlo + row * 264 + c0)     = vlo2[0];
    *(us8*)(atlo + row * 264 + c0 + 8) = vlo2[1];
  }
  __syncthreads();

  // --- AV: wave covers 2 n-tiles in its n-half ---
  const int r = lane & 15, qd = lane >> 4;
  bf16x8 ah[8], al[8];
#pragma unroll
  for (int s = 0; s < 8; ++s) {
    ah[s] = *(const bf16x8*)(athi + r * 264 + qd * 8 + s * 32);
    al[s] = *(const bf16x8*)(atlo + r * 264 + qd * 8 + s * 32);
  }
#pragma unroll
  for (int tI = 0; tI < 2; ++tI) {
    int n0 = (nh << 7) + (wave << 5) + (tI << 4);
    int boff = (b << 16) + (n0 + r) * 256 + qd * 8;
    f32x4 acc = {0.f, 0.f, 0.f, 0.f};
#pragma unroll
    for (int s = 0; s < 8; ++s) {
      bf16x8 bh = *(const bf16x8*)(vhi + boff + s * 32);
      bf16x8 bl = *(const bf16x8*)(vlo + boff + s * 32);
      acc = __builtin_amdgcn_mfma_f32_16x16x32_bf16(ah[s], bh, acc, 0, 0, 0);
      acc = __builtin_amdgcn_mfma_f32_16x16x32_bf16(ah[s], bl, acc, 0, 0, 0);
      acc = __builtin_amdgcn_mfma_f32_16x16x32_bf16(al[s], bh, acc, 0, 0, 0);
    }
#pragma unroll
    for (int i = 0; i < 4; ++i)
      out[(b << 16) + (m0 + qd * 4 + i) * 256 + n0 + r] = acc[i];
  }
}

extern "C" void kernel_launch(void* const* d_in, const int* in_sizes, int n_in,
                              void* d_out, int out_size, void* d_ws, size_t ws_size,
                              hipStream_t stream) {
  const float* queries = (const float*)d_in[0];
  const float* keys    = (const float*)d_in[1];
  const float* values  = (const float*)d_in[2];
  const int*   vlens   = (const int*)d_in[3];
  const float* Wq      = (const float*)d_in[4];
  const float* Wk      = (const float*)d_in[5];
  const float* wv      = (const float*)d_in[6];
  float* out = (float*)d_out;
  char* ws = (char*)d_ws;

  // workspace layout (bytes), total ~17.3 MB
  unsigned short* wt_hi = (unsigned short*)(ws + 0);          // 256 KB
  unsigned short* wt_lo = (unsigned short*)(ws + 262144);     // 256 KB
  unsigned short* vt_hi = (unsigned short*)(ws + 524288);     //   2 MB
  unsigned short* vt_lo = (unsigned short*)(ws + 2621440);    //   2 MB
  float*          R     = (float*)(ws + 4718592);             //   8 MB (q rows || k rows)
  float*          sc    = (float*)(ws + 13107200);            //   4 MB
  float*          wv2   = (float*)(ws + 17301504);            //   1 KB
  float*          Wsum  = (float*)(ws + 17302528);            //   4 B

  tcast_kernel<<<1152, 256, 0, stream>>>(Wq, Wk, values, wv,
                                         wt_hi, wt_lo, vt_hi, vt_lo, wv2, Wsum);
  proj_kernel<<<dim3(256, 4), 256, 0, stream>>>(queries, keys, wt_hi, wt_lo, R);
  scores_kernel<<<dim3(8, 8, 16), 256, 0, stream>>>(R, wv2, Wsum, sc);
  av_fused_kernel<<<dim3(16, 2, 16), 256, 0, stream>>>(sc, vlens, vt_hi, vt_lo, out);
}